// Round 6
// baseline (68.750 us; speedup 1.0000x reference)
//
#include <hip/hip_runtime.h>

// CostVolume via banded-correlation MFMA (v_mfma_f32_16x16x32_f16).
// cost[b,h,w,(sh+4)*9+(sw+4)] = LeakyReLU_0.1( mean_c x1[b,h,w,c]*warped[b,h+sh,w+sw,c] )
// B=8 H=128 W=192 C=128, MD=4. Output fp32 [B,H,W,81].
//
// Round-6: round-4 geometry (59.7us best; TH=8, 16px, 8 waves, RH=16) +
// T14 issue-early/write-late staging split:
//  - warped: LOADRAW(ch) issues raw float4 global loads only; pkh2 cvt +
//    ds_write happen at the TOP OF THE NEXT STEP (load->use = 1 full step,
//    covers L2/HBM latency). Round-4 converted immediately after loading,
//    exposing 200-900cy per step behind only ~150cy of MFMA cover.
//  - x1: 2 rotating raw slots, load->use = 2 steps (x1 has no reuse -> pure
//    HBM ~900cy; round-4's 1-step distance stalled the av pack).
//  - s_setprio(1) around ds_read+MFMA cluster (phase diversity across the
//    ~1.6-2 resident blocks).
// Register cost: +12 (raw warped) +8 (raw x1) arch -> still 3 waves/SIMD
// (combined ~150 <= 170); occupancy intentionally unchanged -- this round
// isolates in-step latency removal. launch_bounds(512,3) honest.
// Round-5 lesson applied: occupancy is pinned ~40% regardless of regs/LDS
// (falsified lever); halo amplification never pays (2nd confirmation).
//
// Everything else as round 4: XCD swizzle (1536 = 8 x 192 = one image per
// XCD), direct band stores (WRITE_SIZE == ideal 63.6MB), lgkm-only
// barriers, conflict-free swizzled staging, double-buffer, K-chunks of 32.

namespace {
constexpr int Bb = 8, Hh = 128, Ww = 192, Cn = 128;
constexpr int MDc = 4;
constexpr int TH = 8, TWT = 16;        // block tile: 8 rows x 16 px
constexpr int NTHR = 512;              // 8 waves
constexpr int RH = 16;                 // staged warped rows  (h0-4 .. h0+11)
constexpr int RPX = 24;                // staged warped px    (w0-4 .. w0+19)
constexpr int KC = 32;                 // channels per chunk
constexpr int NCH = Cn / KC;           // 4
constexpr int KQB = RPX * 16;          // 384 B per kq-plane (24 x 16B slots)
constexpr int ROWB = 4 * KQB;          // 1536 B per staged row
constexpr int BUFB = RH * ROWB;        // 24576 B per buffer
constexpr int RUNS = RH * RPX * 4;     // 1536 8-channel runs per chunk
constexpr int NIT = RUNS / NTHR;       // 3
constexpr float NEG = 0.1f;
}

typedef __fp16 h2v   __attribute__((ext_vector_type(2)));
typedef __fp16 f16x8 __attribute__((ext_vector_type(8)));
typedef float  f32x4 __attribute__((ext_vector_type(4)));

__device__ __forceinline__ unsigned pkh2(float a, float b) {
    h2v h = __builtin_amdgcn_cvt_pkrtz(a, b);
    return __builtin_bit_cast(unsigned, h);
}

// Barrier with LDS-only drain: global prefetch loads stay in flight across it.
__device__ __forceinline__ void barrier_lgkm() {
    asm volatile("s_waitcnt lgkmcnt(0)\n\ts_barrier" ::: "memory");
}

__global__ __launch_bounds__(NTHR, 3)
void costvol_mfma(const float* __restrict__ x1,
                  const float* __restrict__ wp,
                  float* __restrict__ out)
{
    __shared__ __align__(16) unsigned char smem[2 * BUFB];   // 48 KiB

    const int tid  = threadIdx.x;
    const int wv   = tid >> 6;        // 0..7 : h-row within stripe
    const int lane = tid & 63;
    const int nI   = lane & 15;       // A-row m / B-col n lane index
    const int kq   = lane >> 4;       // 0..3 : k-group (8 channels each)

    // XCD swizzle: linear id round-robins across 8 XCDs; remap so XCD x gets
    // 192 consecutive wg = one full batch image (12 x 16 tiles).
    const int id = blockIdx.x;
    const int wg = (id & 7) * 192 + (id >> 3);
    const int bx = wg % 12;
    const int t2 = wg / 12;
    const int by = t2 & 15;
    const int bz = t2 >> 4;

    const int w0 = bx * TWT;
    const int h0 = by * TH;
    const int b  = bz;

    // ---- warped staging decode: run = (row, px, kq), kq innermost ----
    int g_off[NIT]; int l_off[NIT]; bool g_ok[NIT];
#pragma unroll
    for (int it = 0; it < NIT; ++it) {
        int s   = tid + it * NTHR;    // 0..1535
        int skq = s & 3;
        int t   = s >> 2;             // 0..383
        int px  = t % RPX;
        int row = t / RPX;
        int hw  = h0 - MDc + row;
        int ww  = w0 - MDc + px;
        bool ok = (unsigned)hw < (unsigned)Hh && (unsigned)ww < (unsigned)Ww;
        g_ok[it]  = ok;
        g_off[it] = ((b * Hh + (ok ? hw : 0)) * Ww + (ok ? ww : 0)) * Cn + skq * 8;
        l_off[it] = row * ROWB + skq * KQB + ((px ^ (skq << 1)) * 16);
    }

    // T14 split: raw loads issued early, cvt+ds_write one step later.
    float4 gu[NIT], gv[NIT];
    auto LOADRAW = [&](int ch) {
#pragma unroll
        for (int it = 0; it < NIT; ++it) {
            if (g_ok[it]) {
                const float* p = wp + g_off[it] + ch * KC;
                gu[it] = *reinterpret_cast<const float4*>(p);
                gv[it] = *reinterpret_cast<const float4*>(p + 4);
            } else {
                gu[it] = make_float4(0.f, 0.f, 0.f, 0.f);
                gv[it] = make_float4(0.f, 0.f, 0.f, 0.f);
            }
        }
    };
    auto CVTWR = [&](int buf) {
#pragma unroll
        for (int it = 0; it < NIT; ++it) {
            uint4 pk = make_uint4(pkh2(gu[it].x, gu[it].y), pkh2(gu[it].z, gu[it].w),
                                  pkh2(gv[it].x, gv[it].y), pkh2(gv[it].z, gv[it].w));
            *reinterpret_cast<uint4*>(smem + buf * BUFB + l_off[it]) = pk;
        }
    };

    // ---- prologue: chunk0 raw -> x1 slots 0,1 raw -> cvt+write0 -> chunk1 raw
    LOADRAW(0);

    const float* xp = x1 + ((size_t)((b * Hh + h0 + wv) * Ww) + w0 + nI) * Cn + kq * 8;
    float4 xu[2], xv[2];               // rotating raw x1 slots (load->use = 2 steps)
    xu[0] = *reinterpret_cast<const float4*>(xp);
    xv[0] = *reinterpret_cast<const float4*>(xp + 4);
    xu[1] = *reinterpret_cast<const float4*>(xp + KC);
    xv[1] = *reinterpret_cast<const float4*>(xp + KC + 4);

    f32x4 ac0[9], ac1[9];
#pragma unroll
    for (int s = 0; s < 9; ++s) {
        f32x4 z = {0.f, 0.f, 0.f, 0.f};
        ac0[s] = z; ac1[s] = z;
    }

    // per-lane B fragment offset within a staged row; tile1 = ro0 + 128
    const int ro0 = kq * KQB + ((nI ^ (kq << 1)) * 16);

    CVTWR(0);          // chunk 0 -> buf 0 (loads have had x1-issue time to land)
    LOADRAW(1);        // chunk 1 raw, written at top of step 0

    int cur = 0;
#pragma unroll
    for (int ch = 0; ch < NCH; ++ch) {
        barrier_lgkm();
        if (ch + 1 < NCH) CVTWR(cur ^ 1);     // chunk ch+1: raw loaded 1 step ago
        if (ch + 2 < NCH) LOADRAW(ch + 2);    // issue only; no cvt dependency
        // x1: consume slot ch&1 (loaded 2 steps ago), then refill it for ch+2
        f16x8 av;
        {
            int sl = ch & 1;
            uint4 afr = make_uint4(pkh2(xu[sl].x, xu[sl].y), pkh2(xu[sl].z, xu[sl].w),
                                   pkh2(xv[sl].x, xv[sl].y), pkh2(xv[sl].z, xv[sl].w));
            if (ch + 2 < NCH) {
                xu[sl] = *reinterpret_cast<const float4*>(xp + (ch + 2) * KC);
                xv[sl] = *reinterpret_cast<const float4*>(xp + (ch + 2) * KC + 4);
            }
            av = __builtin_bit_cast(f16x8, afr);
        }
        const unsigned char* base = smem + cur * BUFB;
        __builtin_amdgcn_s_setprio(1);
#pragma unroll
        for (int sh = 0; sh < 9; ++sh) {
            const unsigned char* rp = base + (wv + sh) * ROWB;   // staged row ly+sh
            uint4 b0 = *reinterpret_cast<const uint4*>(rp + ro0);
            uint4 b1 = *reinterpret_cast<const uint4*>(rp + ro0 + 128);
            ac0[sh] = __builtin_amdgcn_mfma_f32_16x16x32_f16(
                av, __builtin_bit_cast(f16x8, b0), ac0[sh], 0, 0, 0);
            ac1[sh] = __builtin_amdgcn_mfma_f32_16x16x32_f16(
                av, __builtin_bit_cast(f16x8, b1), ac1[sh], 0, 0, 0);
        }
        __builtin_amdgcn_s_setprio(0);
        cur ^= 1;
    }

    // ---- direct band stores: no LDS round-trip, no barriers ----
    // C/D map: col=n=lane&15, row=m=(lane>>4)*4+reg
    // tile0: staged px p = nI      -> (m, sw4 = nI-m),   valid d=nI-m in [0,8]
    // tile1: staged px p = nI + 8  -> (m, sw4 = nI-m+8), valid d in [-8,0] && nI>=8
    // out k-index = sh*9 + sw4. Active lanes per (rg,sh,tile) write 4
    // contiguous 36B runs (one per kq) -> merged to full lines in L2.
    const float sc = 1.0f / (float)Cn;
    const size_t rowbase = ((size_t)((b * Hh + h0 + wv) * Ww) + w0) * 81;
#pragma unroll
    for (int rg = 0; rg < 4; ++rg) {
        int m = kq * 4 + rg;
        int d = nI - m;
        bool t0 = (d >= 0 && d <= 8);
        bool t1 = (d >= -8 && d <= 0 && nI >= 8);
        size_t mb = rowbase + (size_t)m * 81;
#pragma unroll
        for (int sh = 0; sh < 9; ++sh) {
            if (t0) {
                float v = ac0[sh][rg] * sc;
                v = (v >= 0.f) ? v : NEG * v;
                out[mb + sh * 9 + d] = v;
            }
            if (t1) {
                float v = ac1[sh][rg] * sc;
                v = (v >= 0.f) ? v : NEG * v;
                out[mb + sh * 9 + d + 8] = v;
            }
        }
    }
}

extern "C" void kernel_launch(void* const* d_in, const int* in_sizes, int n_in,
                              void* d_out, int out_size, void* d_ws, size_t ws_size,
                              hipStream_t stream) {
    const float* x1 = (const float*)d_in[0];
    const float* wp = (const float*)d_in[1];
    float* out = (float*)d_out;
    dim3 grid(12 * 16 * 8, 1, 1);   // 1536 blocks, XCD-swizzled in-kernel
    costvol_mfma<<<grid, NTHR, 0, stream>>>(x1, wp, out);
}